// Round 11
// baseline (150.078 us; speedup 1.0000x reference)
//
#include <hip/hip_runtime.h>
#include <math.h>

#define NN   100000
#define E1N  3200000
#define C1N  25000
#define E2N  800000
#define C2N  6250
#define BN   64

#define NBK   782     // buckets, both levels: 99999>>7 = 781; 24999>>5 = 781
#define DPB1  128     // dsts per conv1 agg block (SHIFT=7)
#define DPB2  32      // dsts per conv2 agg block (SHIFT=5)
#define CH1   4096    // edges per agg1 sort chunk (32KB LDS stash)
#define CH2   2048    // edges per agg2 sort chunk (16KB LDS stash)
#define SEPB  2048    // int4 units per count/scatter block (8192 edges)

// ---------------- tiny precompute: factor attention through W ----------------
__global__ void prep_k(const float* __restrict__ W1, const float* __restrict__ att1,
                       const float* __restrict__ W2, const float* __restrict__ att2,
                       float* __restrict__ u, float* __restrict__ v){
  int t = threadIdx.x;
  if (t < 3){
    float a = 0.f, b = 0.f;
    for (int j = 0; j < 16; ++j){ a += W1[t*16+j]*att1[j]; b += W1[t*16+j]*att1[16+j]; }
    u[t] = a; u[3+t] = b;
  }
  if (t >= 8 && t < 24){
    int f = t - 8;
    float a = 0.f, b = 0.f;
    for (int j = 0; j < 32; ++j){ a += W2[f*32+j]*att2[j]; b += W2[f*32+j]*att2[32+j]; }
    v[f] = a; v[16+f] = b;
  }
}

// ---------------- node passes (no h materialization) ----------------

__global__ void node1_k(const float* __restrict__ x, const float* __restrict__ u,
                        float* __restrict__ ad, float4* __restrict__ xp){
  int n = blockIdx.x * blockDim.x + threadIdx.x;
  if (n >= NN) return;
  float x0 = x[n*3+0], x1 = x[n*3+1], x2 = x[n*3+2];
  ad[n] = x0*u[0] + x1*u[1] + x2*u[2];
  xp[n] = make_float4(x0, x1, x2, x0*u[3] + x1*u[4] + x2*u[5]);
}

__global__ void node2_k(const float* __restrict__ hp, const float* __restrict__ v,
                        float* __restrict__ ad2, float* __restrict__ as2){
  int n = blockIdx.x * blockDim.x + threadIdx.x;
  if (n >= C1N) return;
  const float4* hr = (const float4*)(hp + (size_t)n*16);
  float a = 0.f, b = 0.f;
  #pragma unroll
  for (int j = 0; j < 4; ++j){
    float4 hv = hr[j];
    a += hv.x*v[j*4+0] + hv.y*v[j*4+1] + hv.z*v[j*4+2] + hv.w*v[j*4+3];
    b += hv.x*v[16+j*4+0] + hv.y*v[16+j*4+1] + hv.z*v[16+j*4+2] + hv.w*v[16+j*4+3];
  }
  ad2[n] = a; as2[n] = b;
}

// ---------------- bucket count (LDS histogram, zero device atomics) ----------------

template<int SHIFT>
__global__ __launch_bounds__(1024) void bucket_count_k(const int* __restrict__ dst,
                                                       int* __restrict__ cnt,
                                                       int B, int E4){
  __shared__ int hist[NBK];
  int t = threadIdx.x;
  for (int i = t; i < NBK; i += 1024) hist[i] = 0;
  __syncthreads();
  int q0 = blockIdx.x * SEPB;
  int qe = min(q0 + SEPB, E4);
  for (int q = q0 + t; q < qe; q += 1024){
    int4 d4 = ((const int4*)dst)[q];
    atomicAdd(&hist[d4.x >> SHIFT], 1);
    atomicAdd(&hist[d4.y >> SHIFT], 1);
    atomicAdd(&hist[d4.z >> SHIFT], 1);
    atomicAdd(&hist[d4.w >> SHIFT], 1);
  }
  __syncthreads();
  for (int i = t; i < NBK; i += 1024) cnt[(size_t)i * B + blockIdx.x] = hist[i];
}

#define SCAN_T 256

template<int E>
__global__ void scan_block_k(const int* __restrict__ in, int* __restrict__ out,
                             int* __restrict__ bsum, int n){
  __shared__ int lds[SCAN_T];
  int t = threadIdx.x;
  int base = blockIdx.x * (SCAN_T*E);
  int vals[E];
  int acc = 0;
  #pragma unroll
  for (int k = 0; k < E; ++k){
    int i = base + t*E + k;
    vals[k] = (i < n) ? in[i] : 0;
    acc += vals[k];
  }
  lds[t] = acc;
  __syncthreads();
  #pragma unroll
  for (int off = 1; off < SCAN_T; off <<= 1){
    int v = (t >= off) ? lds[t-off] : 0;
    __syncthreads();
    lds[t] += v;
    __syncthreads();
  }
  int run = (t > 0) ? lds[t-1] : 0;
  #pragma unroll
  for (int k = 0; k < E; ++k){
    int i = base + t*E + k;
    run += vals[k];
    if (i < n) out[i] = run;
  }
  if (t == SCAN_T-1) bsum[blockIdx.x] = lds[SCAN_T-1];
}

__global__ void scan_add_k(int* __restrict__ out, const int* __restrict__ bsum, int n){
  int b = blockIdx.x;
  if (b == 0) return;
  int add = bsum[b-1];
  int i0 = b*(SCAN_T*4) + threadIdx.x;
  #pragma unroll
  for (int k = 0; k < 4; ++k){
    int i = i0 + k*SCAN_T;
    if (i < n) out[i] += add;
  }
}

// ---------------- scatter: in-LDS counting sort -> coalesced burst writes ----------------
// Sorts the block's 8192 edges by bucket in LDS, then writes slot-order so each
// 64B sector gets all its stores back-to-back from one wave (one write-through).
template<int SHIFT>
__global__ __launch_bounds__(1024) void bucket_scatter_k(const int* __restrict__ src,
                                                         const int* __restrict__ dst,
                                                         const float* __restrict__ w,
                                                         const int* __restrict__ S,
                                                         int B, int E4,
                                                         int2* __restrict__ pay){
  __shared__ int2 stash[8192];        // 64 KB (scan temp aliases first 4 KB)
  __shared__ int  hcur[NBK];          // histogram, then cursors
  __shared__ int  base_[NBK+1];       // exclusive local offsets (+ total)
  __shared__ int  gstart[NBK];        // global base per (bucket, this block)
  int* sc = (int*)stash;
  int t = threadIdx.x, blk = blockIdx.x;
  for (int i = t; i < NBK; i += 1024){
    hcur[i] = 0;
    size_t g = (size_t)i * B + blk;
    gstart[i] = (g == 0) ? 0 : S[g-1];
  }
  __syncthreads();
  const int MASK = (1 << SHIFT) - 1;
  // phase A: load 8 edges/thread into regs + histogram
  int2 pv[8]; int bk[8]; bool va[8];
  int q0 = blk * SEPB;
  #pragma unroll
  for (int h = 0; h < 2; ++h){
    int q = q0 + h*1024 + t;
    bool v = q < E4;
    int r = h*4;
    if (v){
      int4 s4 = ((const int4*)src)[q];
      int4 d4 = ((const int4*)dst)[q];
      float4 w4 = ((const float4*)w)[q];
      pv[r+0] = make_int2(s4.x | ((d4.x & MASK) << 20), __float_as_int(w4.x)); bk[r+0] = d4.x >> SHIFT;
      pv[r+1] = make_int2(s4.y | ((d4.y & MASK) << 20), __float_as_int(w4.y)); bk[r+1] = d4.y >> SHIFT;
      pv[r+2] = make_int2(s4.z | ((d4.z & MASK) << 20), __float_as_int(w4.z)); bk[r+2] = d4.z >> SHIFT;
      pv[r+3] = make_int2(s4.w | ((d4.w & MASK) << 20), __float_as_int(w4.w)); bk[r+3] = d4.w >> SHIFT;
      atomicAdd(&hcur[bk[r+0]], 1); atomicAdd(&hcur[bk[r+1]], 1);
      atomicAdd(&hcur[bk[r+2]], 1); atomicAdd(&hcur[bk[r+3]], 1);
    }
    va[r+0] = va[r+1] = va[r+2] = va[r+3] = v;
  }
  __syncthreads();
  // phase B: 1024-wide Hillis-Steele scan of padded histogram (sc aliases stash)
  sc[t] = (t < NBK) ? hcur[t] : 0;
  __syncthreads();
  #pragma unroll
  for (int off = 1; off < 1024; off <<= 1){
    int vv = (t >= off) ? sc[t-off] : 0;
    __syncthreads();
    sc[t] += vv;
    __syncthreads();
  }
  int total = sc[1023];
  if (t < NBK) base_[t] = sc[t] - hcur[t];
  if (t == 1023) base_[NBK] = total;
  __syncthreads();
  if (t < NBK) hcur[t] = base_[t];     // cursors (own-slot write, no hazard)
  __syncthreads();                     // sc reads done -> stash may be overwritten
  // phase C: place into sorted LDS stash
  #pragma unroll
  for (int r = 0; r < 8; ++r)
    if (va[r]) stash[atomicAdd(&hcur[bk[r]], 1)] = pv[r];
  __syncthreads();
  // phase D: slot-order write-out; bucket via binary search over base_
  for (int j = t; j < total; j += 1024){
    int lo = 0, hi = NBK;
    while (hi - lo > 1){
      int m = (lo + hi) >> 1;
      if (base_[m] <= j) lo = m; else hi = m;
    }
    pay[gstart[lo] + (j - base_[lo])] = stash[j];
  }
}

// ---------------- conv1 agg: in-LDS counting sort (128 dsts), register accumulation ----------------
__global__ __launch_bounds__(512) void agg1_k(const int* __restrict__ S, int B,
                       const int2* __restrict__ pay,
                       const float* __restrict__ ad, const float4* __restrict__ xp,
                       const float* __restrict__ W1, const float* __restrict__ b1,
                       const int* __restrict__ cl, unsigned* __restrict__ pooled){
  __shared__ float accX[DPB1*5];   // per dst: [s, sx0, sx1, sx2] stride 5
  __shared__ float adL[DPB1];
  __shared__ int   hist[DPB1], base_[DPB1], cur[DPB1];
  __shared__ int   wsum0;
  __shared__ int2  sorted[CH1];
  int t = threadIdx.x, b = blockIdx.x;
  for (int i = t; i < DPB1*5; i += 512) accX[i] = 0.f;
  for (int i = t; i < DPB1; i += 512){
    int gd = b*DPB1 + i;
    adL[i] = (gd < NN) ? ad[gd] : 0.f;
  }
  __syncthreads();
  int beg = b ? S[(size_t)b*B - 1] : 0;
  int end = S[(size_t)(b+1)*B - 1];

  for (int c0 = beg; c0 < end; c0 += CH1){
    if (t < DPB1) hist[t] = 0;
    __syncthreads();
    int2 pv[8]; int dl[8]; bool va[8];
    #pragma unroll
    for (int r = 0; r < 8; ++r){
      int idx = c0 + r*512 + t;
      va[r] = idx < end;
      if (va[r]){ pv[r] = pay[idx]; dl[r] = pv[r].x >> 20; atomicAdd(&hist[dl[r]], 1); }
    }
    __syncthreads();
    int inc = 0, hv_ = 0;
    if (t < DPB1){
      hv_ = hist[t]; inc = hv_;
      #pragma unroll
      for (int off = 1; off < 64; off <<= 1){
        int u_ = __shfl_up(inc, off);
        if ((t & 63) >= off) inc += u_;
      }
      if (t == 63) wsum0 = inc;
    }
    __syncthreads();
    if (t < DPB1){
      int e = inc - hv_ + ((t >= 64) ? wsum0 : 0);
      base_[t] = e; cur[t] = e;
    }
    __syncthreads();
    #pragma unroll
    for (int r = 0; r < 8; ++r)
      if (va[r]) sorted[atomicAdd(&cur[dl[r]], 1)] = pv[r];
    __syncthreads();
    {
      int g = t >> 2, lane = t & 3;
      int cnt = hist[g], bas = base_[g];
      float adg = adL[g];
      float aS = 0.f, a0 = 0.f, a1 = 0.f, a2 = 0.f;
      for (int k = lane; k < cnt; k += 4){
        int2 p = sorted[bas + k];
        float4 xv = xp[p.x & 0xFFFFF];
        float l = adg + xv.w; l = l > 0.f ? l : 0.2f*l;
        float ex = __expf(l);
        float c = ex * __int_as_float(p.y);
        aS += ex; a0 += c*xv.x; a1 += c*xv.y; a2 += c*xv.z;
      }
      #pragma unroll
      for (int off = 1; off < 4; off <<= 1){
        aS += __shfl_xor(aS, off); a0 += __shfl_xor(a0, off);
        a1 += __shfl_xor(a1, off); a2 += __shfl_xor(a2, off);
      }
      if (lane == 0){
        accX[g*5+0] += aS; accX[g*5+1] += a0;
        accX[g*5+2] += a1; accX[g*5+3] += a2;
      }
    }
    __syncthreads();
  }
  for (int i = t; i < DPB1*16; i += 512){
    int d = i >> 4, j = i & 15;
    int gd = b*DPB1 + d;
    if (gd < NN){
      float s = accX[d*5];
      float inv = s > 0.f ? 1.f/s : 0.f;     // no-edge node: out = relu(b1)
      float vl = (accX[d*5+1]*W1[j] + accX[d*5+2]*W1[16+j] + accX[d*5+3]*W1[32+j])*inv + b1[j];
      vl = vl > 0.f ? vl : 0.f;
      int c = cl[gd];
      unsigned nb_ = __float_as_uint(vl);
      unsigned* addr = pooled + (size_t)c*16 + j;
      if (nb_ > *addr) atomicMax(addr, nb_);  // monotonic: stale read safe
    }
  }
}

// ---------------- conv2 agg: in-LDS counting sort, register accumulation ----------------
__global__ __launch_bounds__(512) void agg2_k(const int* __restrict__ S, int B,
                       const int2* __restrict__ pay,
                       const float* __restrict__ ad2, const float* __restrict__ as2,
                       const float* __restrict__ hp, const float* __restrict__ W2,
                       const float* __restrict__ b2, const int* __restrict__ cl2,
                       unsigned* __restrict__ pooledm){
  __shared__ float accH[DPB2*17];  // per dst: 16 feature sums + s at [16]
  __shared__ float adL[DPB2];
  __shared__ int   hist[DPB2], base_[DPB2], cur[DPB2];
  __shared__ int2  sorted[CH2];
  int t = threadIdx.x, b = blockIdx.x;
  for (int i = t; i < DPB2*17; i += 512) accH[i] = 0.f;
  if (t < DPB2){ int gd = b*DPB2 + t; adL[t] = (gd < C1N) ? ad2[gd] : 0.f; }
  __syncthreads();
  int beg = b ? S[(size_t)b*B - 1] : 0;
  int end = S[(size_t)(b+1)*B - 1];

  for (int c0 = beg; c0 < end; c0 += CH2){
    if (t < DPB2) hist[t] = 0;
    __syncthreads();
    int2 pv[4]; int dl[4]; bool va[4];
    #pragma unroll
    for (int r = 0; r < 4; ++r){
      int idx = c0 + r*512 + t;
      va[r] = idx < end;
      if (va[r]){ pv[r] = pay[idx]; dl[r] = pv[r].x >> 20; atomicAdd(&hist[dl[r]], 1); }
    }
    __syncthreads();
    if (t < DPB2){
      int v = hist[t], inc = v;
      #pragma unroll
      for (int off = 1; off < DPB2; off <<= 1){
        int u_ = __shfl_up(inc, off);
        if (t >= off) inc += u_;
      }
      base_[t] = inc - v;
      cur[t]   = inc - v;
    }
    __syncthreads();
    #pragma unroll
    for (int r = 0; r < 4; ++r)
      if (va[r]) sorted[atomicAdd(&cur[dl[r]], 1)] = pv[r];
    __syncthreads();
    {
      int g = t >> 4, lane = t & 15;
      int cnt = hist[g], bas = base_[g];
      float adg = adL[g];
      float aS = 0.f;
      float4 f0 = make_float4(0,0,0,0), f1 = make_float4(0,0,0,0);
      float4 f2 = make_float4(0,0,0,0), f3 = make_float4(0,0,0,0);
      for (int k = lane; k < cnt; k += 16){
        int2 p = sorted[bas + k];
        int sv = p.x & 0xFFFFF;
        float l = adg + as2[sv]; l = l > 0.f ? l : 0.2f*l;
        float ex = __expf(l);
        float c = ex * __int_as_float(p.y);
        const float4* hs = (const float4*)(hp + (size_t)sv*16);
        float4 h0 = hs[0], h1 = hs[1], h2 = hs[2], h3 = hs[3];
        aS += ex;
        f0.x += c*h0.x; f0.y += c*h0.y; f0.z += c*h0.z; f0.w += c*h0.w;
        f1.x += c*h1.x; f1.y += c*h1.y; f1.z += c*h1.z; f1.w += c*h1.w;
        f2.x += c*h2.x; f2.y += c*h2.y; f2.z += c*h2.z; f2.w += c*h2.w;
        f3.x += c*h3.x; f3.y += c*h3.y; f3.z += c*h3.z; f3.w += c*h3.w;
      }
      #pragma unroll
      for (int off = 1; off < 16; off <<= 1){
        aS += __shfl_xor(aS, off);
        f0.x += __shfl_xor(f0.x, off); f0.y += __shfl_xor(f0.y, off);
        f0.z += __shfl_xor(f0.z, off); f0.w += __shfl_xor(f0.w, off);
        f1.x += __shfl_xor(f1.x, off); f1.y += __shfl_xor(f1.y, off);
        f1.z += __shfl_xor(f1.z, off); f1.w += __shfl_xor(f1.w, off);
        f2.x += __shfl_xor(f2.x, off); f2.y += __shfl_xor(f2.y, off);
        f2.z += __shfl_xor(f2.z, off); f2.w += __shfl_xor(f2.w, off);
        f3.x += __shfl_xor(f3.x, off); f3.y += __shfl_xor(f3.y, off);
        f3.z += __shfl_xor(f3.z, off); f3.w += __shfl_xor(f3.w, off);
      }
      if (lane == 0){
        float* a = accH + g*17;
        a[0] += f0.x; a[1] += f0.y; a[2]  += f0.z; a[3]  += f0.w;
        a[4] += f1.x; a[5] += f1.y; a[6]  += f1.z; a[7]  += f1.w;
        a[8] += f2.x; a[9] += f2.y; a[10] += f2.z; a[11] += f2.w;
        a[12]+= f3.x; a[13]+= f3.y; a[14] += f3.z; a[15] += f3.w;
        a[16]+= aS;
      }
    }
    __syncthreads();
  }
  for (int i = t; i < DPB2*32; i += 512){
    int d = i >> 5, j = i & 31;
    int gd = b*DPB2 + d;
    if (gd < C1N){
      float s = accH[d*17+16];
      float inv = s > 0.f ? 1.f/s : 0.f;
      float vl = 0.f;
      #pragma unroll
      for (int f = 0; f < 16; ++f) vl += accH[d*17+f] * W2[f*32+j];
      vl = vl*inv + b2[j];
      vl = vl > 0.f ? vl : 0.f;
      int c = cl2[gd];
      unsigned nb_ = __float_as_uint(vl);
      unsigned* addr = pooledm + (size_t)c*32 + j;
      if (nb_ > *addr) atomicMax(addr, nb_);
    }
  }
}

// ---------------- fused readout (scatter-mean) + MLP head ----------------
// batch_c2 is SORTED: binary-search the [start,end) range per graph.
__global__ void readout_head_k(const float* __restrict__ hm, const int* __restrict__ batch,
                               const float* __restrict__ Wfc1, const float* __restrict__ bfc1,
                               const float* __restrict__ Wfc2, const float* __restrict__ bfc2,
                               float* __restrict__ out){
  __shared__ float gs[32];
  int t = threadIdx.x, b = blockIdx.x;
  if (t < 32) gs[t] = 0.f;
  int lo = 0, hi = C2N;
  while (lo < hi){ int m = (lo+hi)>>1; if (batch[m] < b) lo = m+1; else hi = m; }
  int start = lo;
  hi = C2N;
  while (lo < hi){ int m = (lo+hi)>>1; if (batch[m] < b+1) lo = m+1; else hi = m; }
  int end = lo;
  __syncthreads();
  float g[32];
  #pragma unroll
  for (int j = 0; j < 32; ++j) g[j] = 0.f;
  for (int c = start + t; c < end; c += 256){
    const float4* hv = (const float4*)(hm + (size_t)c*32);
    #pragma unroll
    for (int j = 0; j < 8; ++j){
      float4 v = hv[j];
      g[j*4+0] += v.x; g[j*4+1] += v.y; g[j*4+2] += v.z; g[j*4+3] += v.w;
    }
  }
  #pragma unroll
  for (int j = 0; j < 32; ++j){
    float v = g[j];
    v += __shfl_xor(v, 1);  v += __shfl_xor(v, 2);  v += __shfl_xor(v, 4);
    v += __shfl_xor(v, 8);  v += __shfl_xor(v, 16); v += __shfl_xor(v, 32);
    if ((t & 63) == 0) atomicAdd(&gs[j], v);
  }
  __syncthreads();
  if (t < 64){
    float cnt = (float)(end - start); if (cnt < 1.f) cnt = 1.f;
    float inv = 1.f / cnt;
    float acc = bfc1[t];
    #pragma unroll
    for (int j = 0; j < 32; ++j) acc += gs[j] * inv * Wfc1[j*64 + t];
    acc = acc > 0.f ? acc : 0.f;
    acc *= Wfc2[t];
    acc += __shfl_xor(acc, 1);  acc += __shfl_xor(acc, 2);  acc += __shfl_xor(acc, 4);
    acc += __shfl_xor(acc, 8);  acc += __shfl_xor(acc, 16); acc += __shfl_xor(acc, 32);
    if (t == 0) out[b] = acc + bfc2[0];
  }
}

// ---------------- launch ----------------

extern "C" void kernel_launch(void* const* d_in, const int* in_sizes, int n_in,
                              void* d_out, int out_size, void* d_ws, size_t ws_size,
                              hipStream_t stream) {
  const float* x        = (const float*)d_in[0];
  const int*   ei       = (const int*)  d_in[1];   // [2, E1]: src = ei, dst = ei+E1
  const float* ea       = (const float*)d_in[2];
  const int*   cluster1 = (const int*)  d_in[3];
  const int*   ei2      = (const int*)  d_in[4];   // [2, E2]
  const float* ea2      = (const float*)d_in[5];
  const int*   cluster2 = (const int*)  d_in[6];
  const int*   batch    = (const int*)  d_in[7];
  const float* W1   = (const float*)d_in[8];
  const float* att1 = (const float*)d_in[9];
  const float* b1   = (const float*)d_in[10];
  const float* W2   = (const float*)d_in[11];
  const float* att2 = (const float*)d_in[12];
  const float* b2   = (const float*)d_in[13];
  const float* Wfc1 = (const float*)d_in[14];
  const float* bfc1 = (const float*)d_in[15];
  const float* Wfc2 = (const float*)d_in[16];
  const float* bfc2 = (const float*)d_in[17];

  const int B1 = (E1N/4 + SEPB - 1) / SEPB;    // 391
  const int B2 = (E2N/4 + SEPB - 1) / SEPB;    // 98
  const int n1 = NBK * B1;                     // 305,762
  const int n2 = NBK * B2;                     // 76,636
  const int nb1 = (n1 + SCAN_T*4 - 1) / (SCAN_T*4);  // 299 (<=2048 top capacity)
  const int nb2 = (n2 + SCAN_T*4 - 1) / (SCAN_T*4);  // 75

  float* ws = (float*)d_ws;
  // ---- zero-initialized block (pool buffers only) ----
  float* hp   = ws;                          // C1N*16 (float bits via atomicMax)
  float* hm   = hp + (size_t)C1N*16;         // C2N*32
  char*  zend = (char*)(hm + (size_t)C2N*32);
  size_t zbytes = (size_t)(zend - (char*)ws);
  // ---- write-before-read block (16B aligned) ----
  size_t off16 = (zbytes + 15) & ~(size_t)15;
  int2*   pay1 = (int2*)((char*)ws + off16); // E1N int2
  int2*   pay2 = pay1 + E1N;                 // E2N int2
  float4* xp   = (float4*)(pay2 + E2N);      // NN float4
  float*  ad1  = (float*)(xp + NN);          // NN
  float*  ad2  = ad1 + NN;                   // C1N
  float*  as2  = ad2 + C1N;                  // C1N
  float*  uv   = as2 + C1N;                  // 40 (u[6] at +0, v[32] at +8)
  int*    cnt1 = (int*)(uv + 40);            // n1
  int*    S1   = cnt1 + n1;                  // n1
  int*    cnt2 = S1   + n1;                  // n2
  int*    S2   = cnt2 + n2;                  // n2
  int*    bsum = S2   + n2;                  // 2048
  int*    bsumT= bsum + 2048;                // 8 (dummy)

  hipMemsetAsync(ws, 0, zbytes, stream);

  prep_k<<<1, 64, 0, stream>>>(W1, att1, W2, att2, uv, uv + 8);

  // conv1 (SHIFT=7, DPB1=128)
  node1_k<<<(NN + 255)/256, 256, 0, stream>>>(x, uv, ad1, xp);
  bucket_count_k<7><<<B1, 1024, 0, stream>>>(ei + E1N, cnt1, B1, E1N/4);
  scan_block_k<4><<<nb1, SCAN_T, 0, stream>>>(cnt1, S1, bsum, n1);
  scan_block_k<8><<<1, SCAN_T, 0, stream>>>(bsum, bsum, bsumT, nb1);  // in-place top scan
  scan_add_k<<<nb1, SCAN_T, 0, stream>>>(S1, bsum, n1);
  bucket_scatter_k<7><<<B1, 1024, 0, stream>>>(ei, ei + E1N, ea, S1, B1, E1N/4, pay1);
  agg1_k<<<NBK, 512, 0, stream>>>(S1, B1, pay1, ad1, xp, W1, b1, cluster1, (unsigned*)hp);

  // conv2 (SHIFT=5, DPB2=32)
  node2_k<<<(C1N + 255)/256, 256, 0, stream>>>(hp, uv + 8, ad2, as2);
  bucket_count_k<5><<<B2, 1024, 0, stream>>>(ei2 + E2N, cnt2, B2, E2N/4);
  scan_block_k<4><<<nb2, SCAN_T, 0, stream>>>(cnt2, S2, bsum, n2);
  scan_block_k<8><<<1, SCAN_T, 0, stream>>>(bsum, bsum, bsumT, nb2);
  scan_add_k<<<nb2, SCAN_T, 0, stream>>>(S2, bsum, n2);
  bucket_scatter_k<5><<<B2, 1024, 0, stream>>>(ei2, ei2 + E2N, ea2, S2, B2, E2N/4, pay2);
  agg2_k<<<NBK, 512, 0, stream>>>(S2, B2, pay2, ad2, as2, hp, W2, b2, cluster2, (unsigned*)hm);

  // readout + head
  readout_head_k<<<BN, 256, 0, stream>>>(hm, batch, Wfc1, bfc1, Wfc2, bfc2, (float*)d_out);
}

// Round 12
// 122.693 us; speedup vs baseline: 1.2232x; 1.2232x over previous
//
#include <hip/hip_runtime.h>
#include <math.h>

#define NN   100000
#define E1N  3200000
#define C1N  25000
#define E2N  800000
#define C2N  6250
#define BN   64

#define NBK   782     // buckets, both levels: 99999>>7 = 781; 24999>>5 = 781
#define DPB1  128     // dsts per conv1 agg block (SHIFT=7)
#define DPB2  32      // dsts per conv2 agg block (SHIFT=5)
#define CH1   4096    // edges per agg1 sort chunk (32KB LDS stash)
#define CH2   2048    // edges per agg2 sort chunk (16KB LDS stash)
#define SEPB  2048    // int4 units per count/scatter block (8192 edges)
#define SCAN_T 256

// ---------- front: node1 (u computed in-block) + bucket counts for BOTH levels ----------
__global__ __launch_bounds__(1024) void front_k(
    const float* __restrict__ x, const float* __restrict__ W1, const float* __restrict__ att1,
    float* __restrict__ ad1, float4* __restrict__ xp,
    const int* __restrict__ dst1, int* __restrict__ cnt1, int B1,
    const int* __restrict__ dst2, int* __restrict__ cnt2, int B2){
  __shared__ int hist[NBK];
  __shared__ float uL[6];
  int t = threadIdx.x, blk = blockIdx.x;
  const int NBLK1 = (NN + 1023) / 1024;     // 98
  if (blk < NBLK1){
    // node1 role: ad1 = x.u_d ; xp = (x0,x1,x2, x.u_s)
    if (t < 6){
      int r = t % 3, half = t / 3;
      float a = 0.f;
      #pragma unroll
      for (int j = 0; j < 16; ++j) a += W1[r*16+j] * att1[half*16+j];
      uL[t] = a;
    }
    __syncthreads();
    int n = blk*1024 + t;
    if (n < NN){
      float x0 = x[n*3+0], x1 = x[n*3+1], x2 = x[n*3+2];
      ad1[n] = x0*uL[0] + x1*uL[1] + x2*uL[2];
      xp[n]  = make_float4(x0, x1, x2, x0*uL[3] + x1*uL[4] + x2*uL[5]);
    }
    return;
  }
  // count role (runtime shift)
  int b = blk - NBLK1;
  const int* dst; int* cnt; int B, E4, shift, bb;
  if (b < B1){ dst = dst1; cnt = cnt1; B = B1; E4 = E1N/4; shift = 7; bb = b; }
  else       { dst = dst2; cnt = cnt2; B = B2; E4 = E2N/4; shift = 5; bb = b - B1; }
  for (int i = t; i < NBK; i += 1024) hist[i] = 0;
  __syncthreads();
  int q0 = bb * SEPB, qe = min(q0 + SEPB, E4);
  for (int q = q0 + t; q < qe; q += 1024){
    int4 d4 = ((const int4*)dst)[q];
    atomicAdd(&hist[d4.x >> shift], 1);
    atomicAdd(&hist[d4.y >> shift], 1);
    atomicAdd(&hist[d4.z >> shift], 1);
    atomicAdd(&hist[d4.w >> shift], 1);
  }
  __syncthreads();
  for (int i = t; i < NBK; i += 1024) cnt[(size_t)i * B + bb] = hist[i];
}

// ---------- merged scans over both levels ----------
__global__ void scanA_k(const int* __restrict__ c1, int* __restrict__ S1, int* __restrict__ bs1,
                        int n1, int nb1,
                        const int* __restrict__ c2, int* __restrict__ S2, int* __restrict__ bs2,
                        int n2){
  __shared__ int lds[SCAN_T];
  const int* in; int* out; int* bsum; int n; int blk;
  if ((int)blockIdx.x < nb1){ in=c1; out=S1; bsum=bs1; n=n1; blk=blockIdx.x; }
  else                      { in=c2; out=S2; bsum=bs2; n=n2; blk=blockIdx.x-nb1; }
  int t = threadIdx.x;
  int base = blk * (SCAN_T*4);
  int vals[4]; int acc = 0;
  #pragma unroll
  for (int k = 0; k < 4; ++k){
    int i = base + t*4 + k;
    vals[k] = (i < n) ? in[i] : 0;
    acc += vals[k];
  }
  lds[t] = acc;
  __syncthreads();
  #pragma unroll
  for (int off = 1; off < SCAN_T; off <<= 1){
    int v = (t >= off) ? lds[t-off] : 0;
    __syncthreads();
    lds[t] += v;
    __syncthreads();
  }
  int run = (t > 0) ? lds[t-1] : 0;
  #pragma unroll
  for (int k = 0; k < 4; ++k){
    int i = base + t*4 + k;
    run += vals[k];
    if (i < n) out[i] = run;
  }
  if (t == SCAN_T-1) bsum[blk] = lds[SCAN_T-1];
}

__global__ void scanTop2_k(int* __restrict__ a, int na, int* __restrict__ b, int nb){
  __shared__ int lds[SCAN_T];
  int* p = (blockIdx.x == 0) ? a : b;
  int n  = (blockIdx.x == 0) ? na : nb;
  int t = threadIdx.x;
  int vals[8]; int acc = 0;
  #pragma unroll
  for (int k = 0; k < 8; ++k){
    int i = t*8 + k;
    vals[k] = (i < n) ? p[i] : 0;
    acc += vals[k];
  }
  lds[t] = acc;
  __syncthreads();
  #pragma unroll
  for (int off = 1; off < SCAN_T; off <<= 1){
    int v = (t >= off) ? lds[t-off] : 0;
    __syncthreads();
    lds[t] += v;
    __syncthreads();
  }
  int run = (t > 0) ? lds[t-1] : 0;
  #pragma unroll
  for (int k = 0; k < 8; ++k){
    int i = t*8 + k;
    run += vals[k];
    if (i < n) p[i] = run;
  }
}

__global__ void scanAdd2_k(int* __restrict__ S1, const int* __restrict__ bs1, int n1, int nb1,
                           int* __restrict__ S2, const int* __restrict__ bs2, int n2){
  int* out; const int* bsum; int n; int blk;
  if ((int)blockIdx.x < nb1){ out=S1; bsum=bs1; n=n1; blk=blockIdx.x; }
  else                      { out=S2; bsum=bs2; n=n2; blk=blockIdx.x-nb1; }
  if (blk == 0) return;
  int add = bsum[blk-1];
  int i0 = blk*(SCAN_T*4) + threadIdx.x;
  #pragma unroll
  for (int k = 0; k < 4; ++k){
    int i = i0 + k*SCAN_T;
    if (i < n) out[i] += add;
  }
}

// ---------- merged scatter (both levels): in-LDS counting sort -> coalesced burst writes ----------
__global__ __launch_bounds__(1024) void scatter_k(
    const int* __restrict__ src1, const int* __restrict__ dst1, const float* __restrict__ w1,
    const int* __restrict__ S1, int B1, int2* __restrict__ pay1,
    const int* __restrict__ src2, const int* __restrict__ dst2, const float* __restrict__ w2,
    const int* __restrict__ S2, int B2, int2* __restrict__ pay2){
  __shared__ int2 stash[8192];        // 64 KB sorted stash
  __shared__ int  hcur[NBK];          // histogram, then cursors
  __shared__ int  base_[NBK+1];       // exclusive local offsets (+ total)
  __shared__ int  gstart[NBK];        // global base per (bucket, this block)
  __shared__ int  wsum[16];
  int t = threadIdx.x, blk = blockIdx.x;
  const int* src; const int* dst; const float* w; const int* S;
  int B, E4, shift, bb; int2* pay;
  if (blk < B1){ src=src1; dst=dst1; w=w1; S=S1; B=B1; E4=E1N/4; shift=7; bb=blk;     pay=pay1; }
  else         { src=src2; dst=dst2; w=w2; S=S2; B=B2; E4=E2N/4; shift=5; bb=blk-B1; pay=pay2; }
  for (int i = t; i < NBK; i += 1024){
    hcur[i] = 0;
    size_t g = (size_t)i * B + bb;
    gstart[i] = (g == 0) ? 0 : S[g-1];
  }
  __syncthreads();
  const int MASK = (1 << shift) - 1;
  int q0 = bb * SEPB;
  int qe = min(q0 + SEPB, E4);
  // phase A: 8 edges/thread into regs + LDS histogram
  int2 pv[8]; int bk[8]; bool va[8];
  #pragma unroll
  for (int h = 0; h < 2; ++h){
    int q = q0 + h*1024 + t;
    bool v = q < qe;
    int r = h*4;
    if (v){
      int4 s4 = ((const int4*)src)[q];
      int4 d4 = ((const int4*)dst)[q];
      float4 w4 = ((const float4*)w)[q];
      pv[r+0] = make_int2(s4.x | ((d4.x & MASK) << 20), __float_as_int(w4.x)); bk[r+0] = d4.x >> shift;
      pv[r+1] = make_int2(s4.y | ((d4.y & MASK) << 20), __float_as_int(w4.y)); bk[r+1] = d4.y >> shift;
      pv[r+2] = make_int2(s4.z | ((d4.z & MASK) << 20), __float_as_int(w4.z)); bk[r+2] = d4.z >> shift;
      pv[r+3] = make_int2(s4.w | ((d4.w & MASK) << 20), __float_as_int(w4.w)); bk[r+3] = d4.w >> shift;
      atomicAdd(&hcur[bk[r+0]], 1); atomicAdd(&hcur[bk[r+1]], 1);
      atomicAdd(&hcur[bk[r+2]], 1); atomicAdd(&hcur[bk[r+3]], 1);
    }
    va[r+0] = va[r+1] = va[r+2] = va[r+3] = v;
  }
  __syncthreads();
  // phase B: wave-shfl scan (16 waves -> 3 barriers, no Hillis-Steele)
  {
    int wid = t >> 6, lane = t & 63;
    int v = (t < NBK) ? hcur[t] : 0;
    int inc = v;
    #pragma unroll
    for (int off = 1; off < 64; off <<= 1){
      int u = __shfl_up(inc, off);
      if (lane >= off) inc += u;
    }
    if (lane == 63) wsum[wid] = inc;
    __syncthreads();
    if (t < 16){
      int s = wsum[t], si = s;
      #pragma unroll
      for (int off = 1; off < 16; off <<= 1){
        int u = __shfl_up(si, off);
        if (t >= off) si += u;
      }
      wsum[t] = si - s;               // exclusive wave prefix
    }
    __syncthreads();
    if (t < NBK) base_[t] = inc - v + wsum[wid];
    if (t == 0)  base_[NBK] = 4*(qe - q0);
  }
  __syncthreads();
  if (t < NBK) hcur[t] = base_[t];    // cursors
  __syncthreads();
  // phase C: place into sorted LDS stash
  #pragma unroll
  for (int r = 0; r < 8; ++r)
    if (va[r]) stash[atomicAdd(&hcur[bk[r]], 1)] = pv[r];
  __syncthreads();
  // phase D: slot-order write-out; bucket via binary search over base_
  int total = base_[NBK];
  for (int j = t; j < total; j += 1024){
    int lo = 0, hi = NBK;
    while (hi - lo > 1){
      int m = (lo + hi) >> 1;
      if (base_[m] <= j) lo = m; else hi = m;
    }
    pay[gstart[lo] + (j - base_[lo])] = stash[j];
  }
}

// ---------- conv1 agg: in-LDS counting sort (128 dsts), register accumulation ----------
__global__ __launch_bounds__(512) void agg1_k(const int* __restrict__ S, int B,
                       const int2* __restrict__ pay,
                       const float* __restrict__ ad, const float4* __restrict__ xp,
                       const float* __restrict__ W1, const float* __restrict__ b1,
                       const int* __restrict__ cl, unsigned* __restrict__ pooled){
  __shared__ float accX[DPB1*5];   // per dst: [s, sx0, sx1, sx2] stride 5
  __shared__ float adL[DPB1];
  __shared__ int   hist[DPB1], base_[DPB1], cur[DPB1];
  __shared__ int   wsum0;
  __shared__ int2  sorted[CH1];
  int t = threadIdx.x, b = blockIdx.x;
  for (int i = t; i < DPB1*5; i += 512) accX[i] = 0.f;
  for (int i = t; i < DPB1; i += 512){
    int gd = b*DPB1 + i;
    adL[i] = (gd < NN) ? ad[gd] : 0.f;
  }
  __syncthreads();
  int beg = b ? S[(size_t)b*B - 1] : 0;
  int end = S[(size_t)(b+1)*B - 1];

  for (int c0 = beg; c0 < end; c0 += CH1){
    if (t < DPB1) hist[t] = 0;
    __syncthreads();
    int2 pv[8]; int dl[8]; bool va[8];
    #pragma unroll
    for (int r = 0; r < 8; ++r){
      int idx = c0 + r*512 + t;
      va[r] = idx < end;
      if (va[r]){ pv[r] = pay[idx]; dl[r] = pv[r].x >> 20; atomicAdd(&hist[dl[r]], 1); }
    }
    __syncthreads();
    int inc = 0, hv_ = 0;
    if (t < DPB1){
      hv_ = hist[t]; inc = hv_;
      #pragma unroll
      for (int off = 1; off < 64; off <<= 1){
        int u_ = __shfl_up(inc, off);
        if ((t & 63) >= off) inc += u_;
      }
      if (t == 63) wsum0 = inc;
    }
    __syncthreads();
    if (t < DPB1){
      int e = inc - hv_ + ((t >= 64) ? wsum0 : 0);
      base_[t] = e; cur[t] = e;
    }
    __syncthreads();
    #pragma unroll
    for (int r = 0; r < 8; ++r)
      if (va[r]) sorted[atomicAdd(&cur[dl[r]], 1)] = pv[r];
    __syncthreads();
    {
      int g = t >> 2, lane = t & 3;
      int cnt = hist[g], bas = base_[g];
      float adg = adL[g];
      float aS = 0.f, a0 = 0.f, a1 = 0.f, a2 = 0.f;
      for (int k = lane; k < cnt; k += 4){
        int2 p = sorted[bas + k];
        float4 xv = xp[p.x & 0xFFFFF];
        float l = adg + xv.w; l = l > 0.f ? l : 0.2f*l;
        float ex = __expf(l);
        float c = ex * __int_as_float(p.y);
        aS += ex; a0 += c*xv.x; a1 += c*xv.y; a2 += c*xv.z;
      }
      #pragma unroll
      for (int off = 1; off < 4; off <<= 1){
        aS += __shfl_xor(aS, off); a0 += __shfl_xor(a0, off);
        a1 += __shfl_xor(a1, off); a2 += __shfl_xor(a2, off);
      }
      if (lane == 0){
        accX[g*5+0] += aS; accX[g*5+1] += a0;
        accX[g*5+2] += a1; accX[g*5+3] += a2;
      }
    }
    __syncthreads();
  }
  for (int i = t; i < DPB1*16; i += 512){
    int d = i >> 4, j = i & 15;
    int gd = b*DPB1 + d;
    if (gd < NN){
      float s = accX[d*5];
      float inv = s > 0.f ? 1.f/s : 0.f;     // no-edge node: out = relu(b1)
      float vl = (accX[d*5+1]*W1[j] + accX[d*5+2]*W1[16+j] + accX[d*5+3]*W1[32+j])*inv + b1[j];
      vl = vl > 0.f ? vl : 0.f;
      int c = cl[gd];
      unsigned nb_ = __float_as_uint(vl);
      unsigned* addr = pooled + (size_t)c*16 + j;
      if (nb_ > *addr) atomicMax(addr, nb_);  // monotonic: stale read safe
    }
  }
}

// ---------- node2 (v computed in-block) ----------
__global__ void node2_k(const float* __restrict__ hp, const float* __restrict__ W2,
                        const float* __restrict__ att2,
                        float* __restrict__ ad2, float* __restrict__ as2){
  __shared__ float vL[32];
  int t = threadIdx.x;
  if (t < 32){
    int f = t & 15, half = t >> 4;
    float a = 0.f;
    #pragma unroll
    for (int j = 0; j < 32; ++j) a += W2[f*32+j] * att2[half*32+j];
    vL[half*16+f] = a;
  }
  __syncthreads();
  int n = blockIdx.x * blockDim.x + t;
  if (n >= C1N) return;
  const float4* hr = (const float4*)(hp + (size_t)n*16);
  float a = 0.f, b = 0.f;
  #pragma unroll
  for (int j = 0; j < 4; ++j){
    float4 hv = hr[j];
    a += hv.x*vL[j*4+0] + hv.y*vL[j*4+1] + hv.z*vL[j*4+2] + hv.w*vL[j*4+3];
    b += hv.x*vL[16+j*4+0] + hv.y*vL[16+j*4+1] + hv.z*vL[16+j*4+2] + hv.w*vL[16+j*4+3];
  }
  ad2[n] = a; as2[n] = b;
}

// ---------- conv2 agg: in-LDS counting sort, register accumulation ----------
__global__ __launch_bounds__(512) void agg2_k(const int* __restrict__ S, int B,
                       const int2* __restrict__ pay,
                       const float* __restrict__ ad2, const float* __restrict__ as2,
                       const float* __restrict__ hp, const float* __restrict__ W2,
                       const float* __restrict__ b2, const int* __restrict__ cl2,
                       unsigned* __restrict__ pooledm){
  __shared__ float accH[DPB2*17];  // per dst: 16 feature sums + s at [16]
  __shared__ float adL[DPB2];
  __shared__ int   hist[DPB2], base_[DPB2], cur[DPB2];
  __shared__ int2  sorted[CH2];
  int t = threadIdx.x, b = blockIdx.x;
  for (int i = t; i < DPB2*17; i += 512) accH[i] = 0.f;
  if (t < DPB2){ int gd = b*DPB2 + t; adL[t] = (gd < C1N) ? ad2[gd] : 0.f; }
  __syncthreads();
  int beg = b ? S[(size_t)b*B - 1] : 0;
  int end = S[(size_t)(b+1)*B - 1];

  for (int c0 = beg; c0 < end; c0 += CH2){
    if (t < DPB2) hist[t] = 0;
    __syncthreads();
    int2 pv[4]; int dl[4]; bool va[4];
    #pragma unroll
    for (int r = 0; r < 4; ++r){
      int idx = c0 + r*512 + t;
      va[r] = idx < end;
      if (va[r]){ pv[r] = pay[idx]; dl[r] = pv[r].x >> 20; atomicAdd(&hist[dl[r]], 1); }
    }
    __syncthreads();
    if (t < DPB2){
      int v = hist[t], inc = v;
      #pragma unroll
      for (int off = 1; off < DPB2; off <<= 1){
        int u_ = __shfl_up(inc, off);
        if (t >= off) inc += u_;
      }
      base_[t] = inc - v;
      cur[t]   = inc - v;
    }
    __syncthreads();
    #pragma unroll
    for (int r = 0; r < 4; ++r)
      if (va[r]) sorted[atomicAdd(&cur[dl[r]], 1)] = pv[r];
    __syncthreads();
    {
      int g = t >> 4, lane = t & 15;
      int cnt = hist[g], bas = base_[g];
      float adg = adL[g];
      float aS = 0.f;
      float4 f0 = make_float4(0,0,0,0), f1 = make_float4(0,0,0,0);
      float4 f2 = make_float4(0,0,0,0), f3 = make_float4(0,0,0,0);
      for (int k = lane; k < cnt; k += 16){
        int2 p = sorted[bas + k];
        int sv = p.x & 0xFFFFF;
        float l = adg + as2[sv]; l = l > 0.f ? l : 0.2f*l;
        float ex = __expf(l);
        float c = ex * __int_as_float(p.y);
        const float4* hs = (const float4*)(hp + (size_t)sv*16);
        float4 h0 = hs[0], h1 = hs[1], h2 = hs[2], h3 = hs[3];
        aS += ex;
        f0.x += c*h0.x; f0.y += c*h0.y; f0.z += c*h0.z; f0.w += c*h0.w;
        f1.x += c*h1.x; f1.y += c*h1.y; f1.z += c*h1.z; f1.w += c*h1.w;
        f2.x += c*h2.x; f2.y += c*h2.y; f2.z += c*h2.z; f2.w += c*h2.w;
        f3.x += c*h3.x; f3.y += c*h3.y; f3.z += c*h3.z; f3.w += c*h3.w;
      }
      #pragma unroll
      for (int off = 1; off < 16; off <<= 1){
        aS += __shfl_xor(aS, off);
        f0.x += __shfl_xor(f0.x, off); f0.y += __shfl_xor(f0.y, off);
        f0.z += __shfl_xor(f0.z, off); f0.w += __shfl_xor(f0.w, off);
        f1.x += __shfl_xor(f1.x, off); f1.y += __shfl_xor(f1.y, off);
        f1.z += __shfl_xor(f1.z, off); f1.w += __shfl_xor(f1.w, off);
        f2.x += __shfl_xor(f2.x, off); f2.y += __shfl_xor(f2.y, off);
        f2.z += __shfl_xor(f2.z, off); f2.w += __shfl_xor(f2.w, off);
        f3.x += __shfl_xor(f3.x, off); f3.y += __shfl_xor(f3.y, off);
        f3.z += __shfl_xor(f3.z, off); f3.w += __shfl_xor(f3.w, off);
      }
      if (lane == 0){
        float* a = accH + g*17;
        a[0] += f0.x; a[1] += f0.y; a[2]  += f0.z; a[3]  += f0.w;
        a[4] += f1.x; a[5] += f1.y; a[6]  += f1.z; a[7]  += f1.w;
        a[8] += f2.x; a[9] += f2.y; a[10] += f2.z; a[11] += f2.w;
        a[12]+= f3.x; a[13]+= f3.y; a[14] += f3.z; a[15] += f3.w;
        a[16]+= aS;
      }
    }
    __syncthreads();
  }
  for (int i = t; i < DPB2*32; i += 512){
    int d = i >> 5, j = i & 31;
    int gd = b*DPB2 + d;
    if (gd < C1N){
      float s = accH[d*17+16];
      float inv = s > 0.f ? 1.f/s : 0.f;
      float vl = 0.f;
      #pragma unroll
      for (int f = 0; f < 16; ++f) vl += accH[d*17+f] * W2[f*32+j];
      vl = vl*inv + b2[j];
      vl = vl > 0.f ? vl : 0.f;
      int c = cl2[gd];
      unsigned nb_ = __float_as_uint(vl);
      unsigned* addr = pooledm + (size_t)c*32 + j;
      if (nb_ > *addr) atomicMax(addr, nb_);
    }
  }
}

// ---------- fused readout (scatter-mean, sorted batch -> binary search) + MLP head ----------
__global__ void readout_head_k(const float* __restrict__ hm, const int* __restrict__ batch,
                               const float* __restrict__ Wfc1, const float* __restrict__ bfc1,
                               const float* __restrict__ Wfc2, const float* __restrict__ bfc2,
                               float* __restrict__ out){
  __shared__ float gs[32];
  int t = threadIdx.x, b = blockIdx.x;
  if (t < 32) gs[t] = 0.f;
  int lo = 0, hi = C2N;
  while (lo < hi){ int m = (lo+hi)>>1; if (batch[m] < b) lo = m+1; else hi = m; }
  int start = lo;
  hi = C2N;
  while (lo < hi){ int m = (lo+hi)>>1; if (batch[m] < b+1) lo = m+1; else hi = m; }
  int end = lo;
  __syncthreads();
  float g[32];
  #pragma unroll
  for (int j = 0; j < 32; ++j) g[j] = 0.f;
  for (int c = start + t; c < end; c += 256){
    const float4* hv = (const float4*)(hm + (size_t)c*32);
    #pragma unroll
    for (int j = 0; j < 8; ++j){
      float4 v = hv[j];
      g[j*4+0] += v.x; g[j*4+1] += v.y; g[j*4+2] += v.z; g[j*4+3] += v.w;
    }
  }
  #pragma unroll
  for (int j = 0; j < 32; ++j){
    float v = g[j];
    v += __shfl_xor(v, 1);  v += __shfl_xor(v, 2);  v += __shfl_xor(v, 4);
    v += __shfl_xor(v, 8);  v += __shfl_xor(v, 16); v += __shfl_xor(v, 32);
    if ((t & 63) == 0) atomicAdd(&gs[j], v);
  }
  __syncthreads();
  if (t < 64){
    float cnt = (float)(end - start); if (cnt < 1.f) cnt = 1.f;
    float inv = 1.f / cnt;
    float acc = bfc1[t];
    #pragma unroll
    for (int j = 0; j < 32; ++j) acc += gs[j] * inv * Wfc1[j*64 + t];
    acc = acc > 0.f ? acc : 0.f;
    acc *= Wfc2[t];
    acc += __shfl_xor(acc, 1);  acc += __shfl_xor(acc, 2);  acc += __shfl_xor(acc, 4);
    acc += __shfl_xor(acc, 8);  acc += __shfl_xor(acc, 16); acc += __shfl_xor(acc, 32);
    if (t == 0) out[b] = acc + bfc2[0];
  }
}

// ---------- launch ----------
extern "C" void kernel_launch(void* const* d_in, const int* in_sizes, int n_in,
                              void* d_out, int out_size, void* d_ws, size_t ws_size,
                              hipStream_t stream) {
  const float* x        = (const float*)d_in[0];
  const int*   ei       = (const int*)  d_in[1];   // [2, E1]: src = ei, dst = ei+E1
  const float* ea       = (const float*)d_in[2];
  const int*   cluster1 = (const int*)  d_in[3];
  const int*   ei2      = (const int*)  d_in[4];   // [2, E2]
  const float* ea2      = (const float*)d_in[5];
  const int*   cluster2 = (const int*)  d_in[6];
  const int*   batch    = (const int*)  d_in[7];
  const float* W1   = (const float*)d_in[8];
  const float* att1 = (const float*)d_in[9];
  const float* b1   = (const float*)d_in[10];
  const float* W2   = (const float*)d_in[11];
  const float* att2 = (const float*)d_in[12];
  const float* b2   = (const float*)d_in[13];
  const float* Wfc1 = (const float*)d_in[14];
  const float* bfc1 = (const float*)d_in[15];
  const float* Wfc2 = (const float*)d_in[16];
  const float* bfc2 = (const float*)d_in[17];

  const int B1 = (E1N/4 + SEPB - 1) / SEPB;    // 391
  const int B2 = (E2N/4 + SEPB - 1) / SEPB;    // 98
  const int n1 = NBK * B1;                     // 305,762
  const int n2 = NBK * B2;                     // 76,636
  const int nb1 = (n1 + SCAN_T*4 - 1) / (SCAN_T*4);  // 299 (<=2048 top capacity)
  const int nb2 = (n2 + SCAN_T*4 - 1) / (SCAN_T*4);  // 75
  const int NBLK1 = (NN + 1023) / 1024;        // 98

  float* ws = (float*)d_ws;
  // ---- zero-initialized block (pool buffers only) ----
  float* hp   = ws;                          // C1N*16 (float bits via atomicMax)
  float* hm   = hp + (size_t)C1N*16;         // C2N*32
  char*  zend = (char*)(hm + (size_t)C2N*32);
  size_t zbytes = (size_t)(zend - (char*)ws);
  // ---- write-before-read block (16B aligned) ----
  size_t off16 = (zbytes + 15) & ~(size_t)15;
  int2*   pay1 = (int2*)((char*)ws + off16); // E1N int2
  int2*   pay2 = pay1 + E1N;                 // E2N int2
  float4* xp   = (float4*)(pay2 + E2N);      // NN float4
  float*  ad1  = (float*)(xp + NN);          // NN
  float*  ad2  = ad1 + NN;                   // C1N
  float*  as2  = ad2 + C1N;                  // C1N
  int*    cnt1 = (int*)(as2 + C1N);          // n1
  int*    S1   = cnt1 + n1;                  // n1
  int*    cnt2 = S1   + n1;                  // n2
  int*    S2   = cnt2 + n2;                  // n2
  int*    bsum1= S2   + n2;                  // 2048
  int*    bsum2= bsum1 + 2048;               // 2048

  hipMemsetAsync(ws, 0, zbytes, stream);

  // front: node1 + count1 + count2 (one launch)
  front_k<<<NBLK1 + B1 + B2, 1024, 0, stream>>>(x, W1, att1, ad1, xp,
                                                ei + E1N, cnt1, B1,
                                                ei2 + E2N, cnt2, B2);
  // merged scans (both levels)
  scanA_k<<<nb1 + nb2, SCAN_T, 0, stream>>>(cnt1, S1, bsum1, n1, nb1, cnt2, S2, bsum2, n2);
  scanTop2_k<<<2, SCAN_T, 0, stream>>>(bsum1, nb1, bsum2, nb2);
  scanAdd2_k<<<nb1 + nb2, SCAN_T, 0, stream>>>(S1, bsum1, n1, nb1, S2, bsum2, n2);
  // merged scatter (both levels)
  scatter_k<<<B1 + B2, 1024, 0, stream>>>(ei, ei + E1N, ea, S1, B1, pay1,
                                          ei2, ei2 + E2N, ea2, S2, B2, pay2);
  // conv1 aggregate -> pooled hp
  agg1_k<<<NBK, 512, 0, stream>>>(S1, B1, pay1, ad1, xp, W1, b1, cluster1, (unsigned*)hp);
  // conv2: node transform then aggregate -> pooled hm
  node2_k<<<(C1N + 255)/256, 256, 0, stream>>>(hp, W2, att2, ad2, as2);
  agg2_k<<<NBK, 512, 0, stream>>>(S2, B2, pay2, ad2, as2, hp, W2, b2, cluster2, (unsigned*)hm);
  // readout + head
  readout_head_k<<<BN, 256, 0, stream>>>(hm, batch, Wfc1, bfc1, Wfc2, bfc2, (float*)d_out);
}